// Round 2
// baseline (1225.557 us; speedup 1.0000x reference)
//
#include <hip/hip_runtime.h>
#include <stdint.h>

#define B_ 8
#define S_ 1024
#define D_ 2048
#define H_ 16
#define HD_ 128
#define NROW 8192      // B_*S_
#define NQKV 6144      // 3*D_

typedef __bf16 bf16;
typedef bf16  bf16x8 __attribute__((ext_vector_type(8)));
typedef bf16  bf16x4 __attribute__((ext_vector_type(4)));
typedef float f32x4  __attribute__((ext_vector_type(4)));

#define AS1 __attribute__((address_space(1)))
#define AS3 __attribute__((address_space(3)))

// async global->LDS, 16B per lane; LDS dest = wave-uniform base + lane*16
__device__ __forceinline__ void gl_lds16(const bf16* g, bf16* l) {
  __builtin_amdgcn_global_load_lds((AS1 void*)g, (AS3 void*)l, 16, 0, 0);
}

// ---------- fp32 -> bf16 (x4 vectorized) ----------
__global__ __launch_bounds__(256) void f2b4(const float* __restrict__ in,
                                            bf16* __restrict__ out, int n4) {
  int i = blockIdx.x * 256 + threadIdx.x;
  if (i >= n4) return;
  float4 v = reinterpret_cast<const float4*>(in)[i];
  bf16x4 o;
  o.x = (bf16)v.x; o.y = (bf16)v.y; o.z = (bf16)v.z; o.w = (bf16)v.w;
  reinterpret_cast<bf16x4*>(out)[i] = o;
}

// ---------- pack bq|bk|bv into one 6144 fp32 vector ----------
__global__ void packb(const float* __restrict__ a, const float* __restrict__ b,
                      const float* __restrict__ c, float* __restrict__ o) {
  int i = blockIdx.x * 256 + threadIdx.x;
  if (i >= NQKV) return;
  o[i] = (i < 2048) ? a[i] : (i < 4096 ? b[i - 2048] : c[i - 4096]);
}

// ---------- m97-style GEMM: C[M,N] = A[M,K] * B[N,K]^T + bias ----------
template <typename CT>
__global__ __launch_bounds__(256) void gemm_bt(const bf16* __restrict__ A,
                                               const bf16* __restrict__ Bm,
                                               const float* __restrict__ bias,
                                               CT* __restrict__ C,
                                               int M, int N, int K) {
  __shared__ __align__(16) bf16 As[128 * 32];
  __shared__ __align__(16) bf16 Bs[128 * 32];
  const int tid = threadIdx.x;
  const int w = tid >> 6, l = tid & 63;
  const int wm = (w & 1) * 64, wn = (w >> 1) * 64;
  const int m0 = blockIdx.y * 128, n0 = blockIdx.x * 128;
  const int lr = l & 15, lk = (l >> 4) * 8;
  const int er = (l >> 4) * 4;

  const bf16* ag = A + (long)(m0 + (tid >> 2)) * K + (tid & 3) * 8;
  const bf16* bg = Bm + (long)(n0 + (tid >> 2)) * K + (tid & 3) * 8;
  bf16* al = As + (w * 16) * 32;
  bf16* bl = Bs + (w * 16) * 32;

  f32x4 acc[4][4] = {};

  for (int k0 = 0; k0 < K; k0 += 32) {
    gl_lds16(ag + k0,                 al);
    gl_lds16(ag + (long)64 * K + k0,  al + 64 * 32);
    gl_lds16(bg + k0,                 bl);
    gl_lds16(bg + (long)64 * K + k0,  bl + 64 * 32);
    __syncthreads();
    bf16x8 af[4], bfr[4];
#pragma unroll
    for (int mi = 0; mi < 4; mi++)
      af[mi] = *reinterpret_cast<const bf16x8*>(As + (wm + mi * 16 + lr) * 32 + lk);
#pragma unroll
    for (int ni = 0; ni < 4; ni++)
      bfr[ni] = *reinterpret_cast<const bf16x8*>(Bs + (wn + ni * 16 + lr) * 32 + lk);
#pragma unroll
    for (int mi = 0; mi < 4; mi++)
#pragma unroll
      for (int ni = 0; ni < 4; ni++)
        acc[mi][ni] = __builtin_amdgcn_mfma_f32_16x16x32_bf16(af[mi], bfr[ni], acc[mi][ni], 0, 0, 0);
    __syncthreads();
  }

#pragma unroll
  for (int mi = 0; mi < 4; mi++) {
#pragma unroll
    for (int ni = 0; ni < 4; ni++) {
      const int col = n0 + wn + ni * 16 + lr;
      const float bv = bias[col];
      const long base = (long)(m0 + wm + mi * 16 + er) * N + col;
#pragma unroll
      for (int r = 0; r < 4; r++)
        C[base + (long)r * N] = (CT)(acc[mi][ni][r] + bv);
    }
  }
}

// ---------- in-place RoPE on Q/K (first 64 dims of each head) ----------
__global__ __launch_bounds__(256) void rope_qk(bf16* __restrict__ QKV,
                                               const float* __restrict__ ch,
                                               const float* __restrict__ sh) {
  int idx = blockIdx.x * 256 + threadIdx.x;
  if (idx >= NROW * H_ * 2 * 32) return;
  int hd = idx & 31;
  int qk = (idx >> 5) & 1;
  int h  = (idx >> 6) & 15;
  int row = idx >> 10;             // 0..8191 = (b,s)
  int s = row & (S_ - 1);
  long base = (long)row * NQKV + qk * 2048 + h * HD_ + hd;
  float a  = (float)QKV[base];
  float b2 = (float)QKV[base + 32];
  float c = ch[s * 32 + hd], sn = sh[s * 32 + hd];
  QKV[base]      = (bf16)(a * c - b2 * sn);
  QKV[base + 32] = (bf16)(b2 * c + a * sn);
}

// ---------- V transpose: QKV V-region (b,s,h,hd) -> Vt[b,h,hd,t] ----------
__global__ __launch_bounds__(256) void vtrans(const bf16* __restrict__ QKV,
                                              bf16* __restrict__ Vt) {
  __shared__ unsigned short T[128 * 130];
  const int bid = blockIdx.x;          // bh*8 + tb
  const int tb = bid & 7, bh = bid >> 3;
  const int b = bh >> 4, h = bh & 15;
  const int tid = threadIdx.x;
  const bf16* src = QKV + (long)(b * S_ + tb * 128) * NQKV + 4096 + h * HD_;
#pragma unroll
  for (int it = 0; it < 8; it++) {
    int chunk = it * 256 + tid;
    int r = chunk >> 4, hc = (chunk & 15) * 8;
    bf16x8 v = *reinterpret_cast<const bf16x8*>(src + (long)r * NQKV + hc);
    union { bf16x8 v8; unsigned short u[8]; } u8; u8.v8 = v;
#pragma unroll
    for (int j = 0; j < 8; j++) T[r * 130 + hc + j] = u8.u[j];
  }
  __syncthreads();
  bf16* dst = Vt + (long)bh * HD_ * S_ + tb * 128;
#pragma unroll
  for (int it = 0; it < 8; it++) {
    int chunk = it * 256 + tid;
    int hd = chunk >> 4, tc = (chunk & 15) * 8;
    union { bf16x8 v8; unsigned short u[8]; } u8;
#pragma unroll
    for (int j = 0; j < 8; j++) u8.u[j] = T[(tc + j) * 130 + hd];
    *reinterpret_cast<bf16x8*>(dst + (long)hd * S_ + tc) = u8.v8;
  }
}

// ---------- fused attention, chunk-XOR-swizzled LDS ----------
// LDS tile = 128 rows x 16 chunks (chunk = 8 bf16 = 16B).
// physical chunk = logical chunk ^ (row & 15)  -> 2-way max bank aliasing (free).
// Staging pre-swizzles by permuting the global column each lane fetches.
__device__ __forceinline__ const bf16x8* swz_rd(const bf16* base, int r, int c8) {
  return reinterpret_cast<const bf16x8*>(base + r * 128 + ((c8 ^ (r & 15)) << 3));
}

__global__ __launch_bounds__(256, 2) void attn(const bf16* __restrict__ QKV,
                                               const bf16* __restrict__ Vt,
                                               const float* __restrict__ mask,
                                               bf16* __restrict__ Ob) {
  __shared__ __align__(16) bf16 Ks[128 * 128];   // K tile, reused as P tile
  __shared__ __align__(16) bf16 Vs[128 * 128];   // V^T tile [hd][t]
  const int bid = blockIdx.x;                    // bh*8 + qt
  const int qt = bid & 7, bh = bid >> 3;
  const int b = bh >> 4, h = bh & 15;
  const int q0 = qt * 128;
  const int tid = threadIdx.x, w = tid >> 6, l = tid & 63;
  const int wm = (w & 1) * 64, wn = (w >> 1) * 64;
  const int lr = l & 15, lk = (l >> 4) * 8;
  const int lq = l >> 4;                          // quad id 0..3
  const int er = lq * 4;

  // Q fragments in registers (reused across all 8 t-tiles)
  bf16x8 qf[4][4];
  const bf16* qbase = QKV + (long)(b * S_ + q0) * NQKV + h * HD_;
#pragma unroll
  for (int mi = 0; mi < 4; mi++)
#pragma unroll
    for (int kk = 0; kk < 4; kk++)
      qf[mi][kk] = *reinterpret_cast<const bf16x8*>(
          qbase + (long)(wm + mi * 16 + lr) * NQKV + kk * 32 + lk);

  f32x4 oacc[4][4] = {};

  // staging: lane covers row (tid>>4)+16*i, swizzled source chunk (tid&15)^(tid>>4)
  const int srow = tid >> 4;                      // 0..15
  const int schk = (tid & 15) ^ srow;             // swizzled source chunk
  const bf16* kg = QKV + (long)(b * S_ + srow) * NQKV + 2048 + h * HD_ + schk * 8;
  const bf16* vg = Vt + ((long)bh * HD_ + srow) * S_ + schk * 8;
  bf16* kl = Ks + (w * 4) * 128;
  bf16* vl = Vs + (w * 4) * 128;

  for (int tt = 0; tt < 8; tt++) {
    const int t0 = tt * 128;
#pragma unroll
    for (int i = 0; i < 8; i++) {
      gl_lds16(kg + (long)(t0 + i * 16) * NQKV, kl + (i * 16) * 128);
      gl_lds16(vg + (long)(i * 16) * S_ + t0,   vl + (i * 16) * 128);
    }
    __syncthreads();

    // P = Q K^T  (M=s, N=t, K=hd)
    f32x4 pacc[4][4] = {};
#pragma unroll
    for (int kk = 0; kk < 4; kk++) {
      bf16x8 bfr[4];
#pragma unroll
      for (int ni = 0; ni < 4; ni++)
        bfr[ni] = *swz_rd(Ks, wn + ni * 16 + lr, kk * 4 + lq);
#pragma unroll
      for (int mi = 0; mi < 4; mi++)
#pragma unroll
        for (int ni = 0; ni < 4; ni++)
          pacc[mi][ni] = __builtin_amdgcn_mfma_f32_16x16x32_bf16(qf[mi][kk], bfr[ni], pacc[mi][ni], 0, 0, 0);
    }
    __syncthreads();

    // P + mask -> bf16 into Ks (row = s_local, col = t_local), swizzled
#pragma unroll
    for (int mi = 0; mi < 4; mi++)
#pragma unroll
      for (int ni = 0; ni < 4; ni++) {
        const int tl = wn + ni * 16 + lr;
        const int tc = tl >> 3, tw = tl & 7;
#pragma unroll
        for (int r = 0; r < 4; r++) {
          const int sl = wm + mi * 16 + er + r;
          float v = pacc[mi][ni][r] + mask[(long)(q0 + sl) * S_ + t0 + tl];
          Ks[sl * 128 + ((tc ^ (sl & 15)) << 3) + tw] = (bf16)v;
        }
      }
    __syncthreads();

    // O += P V  (M=s, N=hd, K=t); B-operand = V^T from Vs
#pragma unroll
    for (int kk = 0; kk < 4; kk++) {
      bf16x8 af[4], bfr[4];
#pragma unroll
      for (int mi = 0; mi < 4; mi++)
        af[mi] = *swz_rd(Ks, wm + mi * 16 + lr, kk * 4 + lq);
#pragma unroll
      for (int ni = 0; ni < 4; ni++)
        bfr[ni] = *swz_rd(Vs, wn + ni * 16 + lr, kk * 4 + lq);
#pragma unroll
      for (int mi = 0; mi < 4; mi++)
#pragma unroll
        for (int ni = 0; ni < 4; ni++)
          oacc[mi][ni] = __builtin_amdgcn_mfma_f32_16x16x32_bf16(af[mi], bfr[ni], oacc[mi][ni], 0, 0, 0);
    }
    __syncthreads();
  }

  // write a_sum (bf16) at (b,s, h*128+hd)
#pragma unroll
  for (int mi = 0; mi < 4; mi++)
#pragma unroll
    for (int ni = 0; ni < 4; ni++) {
      const int col = h * HD_ + wn + ni * 16 + lr;
#pragma unroll
      for (int r = 0; r < 4; r++) {
        const int sl = wm + mi * 16 + er + r;
        Ob[(long)(b * S_ + q0 + sl) * D_ + col] = (bf16)oacc[mi][ni][r];
      }
    }
}

extern "C" void kernel_launch(void* const* d_in, const int* in_sizes, int n_in,
                              void* d_out, int out_size, void* d_ws, size_t ws_size,
                              hipStream_t stream) {
  const float* x   = (const float*)d_in[0];
  const float* wq  = (const float*)d_in[1];
  const float* bq  = (const float*)d_in[2];
  const float* wk  = (const float*)d_in[3];
  const float* bk  = (const float*)d_in[4];
  const float* wv  = (const float*)d_in[5];
  const float* bv  = (const float*)d_in[6];
  const float* wo  = (const float*)d_in[7];
  const float* bo  = (const float*)d_in[8];
  const float* ch  = (const float*)d_in[9];
  const float* sh  = (const float*)d_in[10];
  const float* mask = (const float*)d_in[11];
  float* out = (float*)d_out;

  char* ws = (char*)d_ws;
  bf16* xb    = (bf16*)(ws);                  // 32 MB (reused as Ob after GEMM1)
  bf16* wqkvb = (bf16*)(ws + 33554432);       // 24 MB
  bf16* wob   = (bf16*)(ws + 58720256);       // 8 MB
  float* bqkv = (float*)(ws + 67108864);      // 24 KB
  bf16* QKV   = (bf16*)(ws + 67133440);       // 96 MB
  bf16* Vt    = (bf16*)(ws + 167796736);      // 32 MB
  bf16* Ob    = xb;                           // alias: xb dead after GEMM1

  f2b4<<<16384, 256, 0, stream>>>(x, xb, 4194304);
  f2b4<<<4096, 256, 0, stream>>>(wq, wqkvb,           1048576);
  f2b4<<<4096, 256, 0, stream>>>(wk, wqkvb + 4194304, 1048576);
  f2b4<<<4096, 256, 0, stream>>>(wv, wqkvb + 8388608, 1048576);
  f2b4<<<4096, 256, 0, stream>>>(wo, wob, 1048576);
  packb<<<24, 256, 0, stream>>>(bq, bk, bv, bqkv);

  // QKV = x @ [wq;wk;wv]^T + bias  (8192 x 6144 x 2048)
  gemm_bt<bf16><<<dim3(48, 64), 256, 0, stream>>>(xb, wqkvb, bqkv, QKV, NROW, NQKV, D_);

  rope_qk<<<32768, 256, 0, stream>>>(QKV, ch, sh);
  vtrans<<<1024, 256, 0, stream>>>(QKV, Vt);
  attn<<<1024, 256, 0, stream>>>(QKV, Vt, mask, Ob);

  // out = a_sum @ wo^T + bo  (8192 x 2048 x 2048), fp32 output
  gemm_bt<float><<<dim3(16, 64), 256, 0, stream>>>(Ob, wob, bo, out, NROW, D_, D_);
}

// Round 4
// 871.926 us; speedup vs baseline: 1.4056x; 1.4056x over previous
//
#include <hip/hip_runtime.h>
#include <stdint.h>

#define B_ 8
#define S_ 1024
#define D_ 2048
#define H_ 16
#define HD_ 128
#define NROW 8192      // B_*S_
#define NQKV 6144      // 3*D_

typedef __bf16 bf16;
typedef bf16  bf16x8 __attribute__((ext_vector_type(8)));
typedef bf16  bf16x4 __attribute__((ext_vector_type(4)));
typedef float f32x4  __attribute__((ext_vector_type(4)));

#define AS1 __attribute__((address_space(1)))
#define AS3 __attribute__((address_space(3)))

// async global->LDS, 16B per lane; LDS dest = wave-uniform base + lane*16
__device__ __forceinline__ void gl_lds16(const bf16* g, bf16* l) {
  __builtin_amdgcn_global_load_lds((AS1 void*)g, (AS3 void*)l, 16, 0, 0);
}

// ---------- fp32 -> bf16 (x4 vectorized) ----------
__global__ __launch_bounds__(256) void f2b4(const float* __restrict__ in,
                                            bf16* __restrict__ out, int n4) {
  int i = blockIdx.x * 256 + threadIdx.x;
  if (i >= n4) return;
  float4 v = reinterpret_cast<const float4*>(in)[i];
  bf16x4 o;
  o.x = (bf16)v.x; o.y = (bf16)v.y; o.z = (bf16)v.z; o.w = (bf16)v.w;
  reinterpret_cast<bf16x4*>(out)[i] = o;
}

// ---------- pack bq|bk|bv into one 6144 fp32 vector ----------
__global__ void packb(const float* __restrict__ a, const float* __restrict__ b,
                      const float* __restrict__ c, float* __restrict__ o) {
  int i = blockIdx.x * 256 + threadIdx.x;
  if (i >= NQKV) return;
  o[i] = (i < 2048) ? a[i] : (i < 4096 ? b[i - 2048] : c[i - 4096]);
}

// ---------- m97-style GEMM: C[M,N] = A[M,K] * B[N,K]^T + bias ----------
template <typename CT>
__global__ __launch_bounds__(256) void gemm_bt(const bf16* __restrict__ A,
                                               const bf16* __restrict__ Bm,
                                               const float* __restrict__ bias,
                                               CT* __restrict__ C,
                                               int M, int N, int K) {
  __shared__ __align__(16) bf16 As[128 * 32];
  __shared__ __align__(16) bf16 Bs[128 * 32];
  const int tid = threadIdx.x;
  const int w = tid >> 6, l = tid & 63;
  const int wm = (w & 1) * 64, wn = (w >> 1) * 64;
  const int m0 = blockIdx.y * 128, n0 = blockIdx.x * 128;
  const int lr = l & 15, lk = (l >> 4) * 8;
  const int er = (l >> 4) * 4;

  const bf16* ag = A + (long)(m0 + (tid >> 2)) * K + (tid & 3) * 8;
  const bf16* bg = Bm + (long)(n0 + (tid >> 2)) * K + (tid & 3) * 8;
  bf16* al = As + (w * 16) * 32;
  bf16* bl = Bs + (w * 16) * 32;

  f32x4 acc[4][4] = {};

  for (int k0 = 0; k0 < K; k0 += 32) {
    gl_lds16(ag + k0,                 al);
    gl_lds16(ag + (long)64 * K + k0,  al + 64 * 32);
    gl_lds16(bg + k0,                 bl);
    gl_lds16(bg + (long)64 * K + k0,  bl + 64 * 32);
    __syncthreads();
    bf16x8 af[4], bfr[4];
#pragma unroll
    for (int mi = 0; mi < 4; mi++)
      af[mi] = *reinterpret_cast<const bf16x8*>(As + (wm + mi * 16 + lr) * 32 + lk);
#pragma unroll
    for (int ni = 0; ni < 4; ni++)
      bfr[ni] = *reinterpret_cast<const bf16x8*>(Bs + (wn + ni * 16 + lr) * 32 + lk);
#pragma unroll
    for (int mi = 0; mi < 4; mi++)
#pragma unroll
      for (int ni = 0; ni < 4; ni++)
        acc[mi][ni] = __builtin_amdgcn_mfma_f32_16x16x32_bf16(af[mi], bfr[ni], acc[mi][ni], 0, 0, 0);
    __syncthreads();
  }

#pragma unroll
  for (int mi = 0; mi < 4; mi++) {
#pragma unroll
    for (int ni = 0; ni < 4; ni++) {
      const int col = n0 + wn + ni * 16 + lr;
      const float bv = bias[col];
      const long base = (long)(m0 + wm + mi * 16 + er) * N + col;
#pragma unroll
      for (int r = 0; r < 4; r++)
        C[base + (long)r * N] = (CT)(acc[mi][ni][r] + bv);
    }
  }
}

// ---------- in-place RoPE on Q/K (first 64 dims of each head) ----------
__global__ __launch_bounds__(256) void rope_qk(bf16* __restrict__ QKV,
                                               const float* __restrict__ ch,
                                               const float* __restrict__ sh) {
  int idx = blockIdx.x * 256 + threadIdx.x;
  if (idx >= NROW * H_ * 2 * 32) return;
  int hd = idx & 31;
  int qk = (idx >> 5) & 1;
  int h  = (idx >> 6) & 15;
  int row = idx >> 10;             // 0..8191 = (b,s)
  int s = row & (S_ - 1);
  long base = (long)row * NQKV + qk * 2048 + h * HD_ + hd;
  float a  = (float)QKV[base];
  float b2 = (float)QKV[base + 32];
  float c = ch[s * 32 + hd], sn = sh[s * 32 + hd];
  QKV[base]      = (bf16)(a * c - b2 * sn);
  QKV[base + 32] = (bf16)(b2 * c + a * sn);
}

// ---------- V transpose: QKV V-region (b,s,h,hd) -> Vt[b,h,hd,t] ----------
__global__ __launch_bounds__(256) void vtrans(const bf16* __restrict__ QKV,
                                              bf16* __restrict__ Vt) {
  __shared__ unsigned short T[128 * 130];
  const int bid = blockIdx.x;          // bh*8 + tb
  const int tb = bid & 7, bh = bid >> 3;
  const int b = bh >> 4, h = bh & 15;
  const int tid = threadIdx.x;
  const bf16* src = QKV + (long)(b * S_ + tb * 128) * NQKV + 4096 + h * HD_;
#pragma unroll
  for (int it = 0; it < 8; it++) {
    int chunk = it * 256 + tid;
    int r = chunk >> 4, hc = (chunk & 15) * 8;
    bf16x8 v = *reinterpret_cast<const bf16x8*>(src + (long)r * NQKV + hc);
    union { bf16x8 v8; unsigned short u[8]; } u8; u8.v8 = v;
#pragma unroll
    for (int j = 0; j < 8; j++) T[r * 130 + hc + j] = u8.u[j];
  }
  __syncthreads();
  bf16* dst = Vt + (long)bh * HD_ * S_ + tb * 128;
#pragma unroll
  for (int it = 0; it < 8; it++) {
    int chunk = it * 256 + tid;
    int hd = chunk >> 4, tc = (chunk & 15) * 8;
    union { bf16x8 v8; unsigned short u[8]; } u8;
#pragma unroll
    for (int j = 0; j < 8; j++) u8.u[j] = T[(tc + j) * 130 + hd];
    *reinterpret_cast<bf16x8*>(dst + (long)hd * S_ + tc) = u8.v8;
  }
}

// ---------- pass A: S[bhz][1024][1024] = Q_bh K_bh^T + mask ----------
__global__ __launch_bounds__(256) void qk_gemm(const bf16* __restrict__ QKV,
                                               const float* __restrict__ mask,
                                               bf16* __restrict__ Sb, int bh0) {
  __shared__ __align__(16) bf16 As[128 * 32];
  __shared__ __align__(16) bf16 Bs[128 * 32];
  const int z = blockIdx.z;
  const int bh = bh0 + z, b = bh >> 4, h = bh & 15;
  const int m0 = blockIdx.y * 128, n0 = blockIdx.x * 128;
  const int tid = threadIdx.x;
  const int w = tid >> 6, l = tid & 63;
  const int wm = (w & 1) * 64, wn = (w >> 1) * 64;
  const int lr = l & 15, lk = (l >> 4) * 8;
  const int er = (l >> 4) * 4;

  const bf16* ag = QKV + (long)(b * S_ + m0 + (tid >> 2)) * NQKV + h * HD_ + (tid & 3) * 8;
  const bf16* bg = QKV + (long)(b * S_ + n0 + (tid >> 2)) * NQKV + 2048 + h * HD_ + (tid & 3) * 8;
  bf16* al = As + (w * 16) * 32;
  bf16* bl = Bs + (w * 16) * 32;

  f32x4 acc[4][4] = {};

#pragma unroll
  for (int k0 = 0; k0 < HD_; k0 += 32) {
    gl_lds16(ag + k0,                    al);
    gl_lds16(ag + (long)64 * NQKV + k0,  al + 64 * 32);
    gl_lds16(bg + k0,                    bl);
    gl_lds16(bg + (long)64 * NQKV + k0,  bl + 64 * 32);
    __syncthreads();
    bf16x8 af[4], bfr[4];
#pragma unroll
    for (int mi = 0; mi < 4; mi++)
      af[mi] = *reinterpret_cast<const bf16x8*>(As + (wm + mi * 16 + lr) * 32 + lk);
#pragma unroll
    for (int ni = 0; ni < 4; ni++)
      bfr[ni] = *reinterpret_cast<const bf16x8*>(Bs + (wn + ni * 16 + lr) * 32 + lk);
#pragma unroll
    for (int mi = 0; mi < 4; mi++)
#pragma unroll
      for (int ni = 0; ni < 4; ni++)
        acc[mi][ni] = __builtin_amdgcn_mfma_f32_16x16x32_bf16(af[mi], bfr[ni], acc[mi][ni], 0, 0, 0);
    __syncthreads();
  }

  bf16* Sout = Sb + (long)z * S_ * S_;
#pragma unroll
  for (int mi = 0; mi < 4; mi++) {
#pragma unroll
    for (int ni = 0; ni < 4; ni++) {
      const int tl = n0 + wn + ni * 16 + lr;
#pragma unroll
      for (int r = 0; r < 4; r++) {
        const int sl = m0 + wm + mi * 16 + er + r;
        Sout[(long)sl * S_ + tl] = (bf16)(acc[mi][ni][r] + mask[(long)sl * S_ + tl]);
      }
    }
  }
}

// ---------- pass B: Ob rows = S_bh * V_bh (B-operand = Vt rows) ----------
__global__ __launch_bounds__(256) void pv_gemm(const bf16* __restrict__ Sb,
                                               const bf16* __restrict__ Vt,
                                               bf16* __restrict__ Ob, int bh0) {
  __shared__ __align__(16) bf16 As[128 * 32];
  __shared__ __align__(16) bf16 Bs[128 * 32];
  const int z = blockIdx.z;
  const int bh = bh0 + z, b = bh >> 4, h = bh & 15;
  const int m0 = blockIdx.y * 128;
  const int tid = threadIdx.x;
  const int w = tid >> 6, l = tid & 63;
  const int wm = (w & 1) * 64, wn = (w >> 1) * 64;
  const int lr = l & 15, lk = (l >> 4) * 8;
  const int er = (l >> 4) * 4;

  const bf16* ag = Sb + ((long)z * S_ + m0 + (tid >> 2)) * S_ + (tid & 3) * 8;
  const bf16* bg = Vt + ((long)bh * HD_ + (tid >> 2)) * S_ + (tid & 3) * 8;
  bf16* al = As + (w * 16) * 32;
  bf16* bl = Bs + (w * 16) * 32;

  f32x4 acc[4][4] = {};

  for (int k0 = 0; k0 < S_; k0 += 32) {
    gl_lds16(ag + k0,                  al);
    gl_lds16(ag + (long)64 * S_ + k0,  al + 64 * 32);
    gl_lds16(bg + k0,                  bl);
    gl_lds16(bg + (long)64 * S_ + k0,  bl + 64 * 32);
    __syncthreads();
    bf16x8 af[4], bfr[4];
#pragma unroll
    for (int mi = 0; mi < 4; mi++)
      af[mi] = *reinterpret_cast<const bf16x8*>(As + (wm + mi * 16 + lr) * 32 + lk);
#pragma unroll
    for (int ni = 0; ni < 4; ni++)
      bfr[ni] = *reinterpret_cast<const bf16x8*>(Bs + (wn + ni * 16 + lr) * 32 + lk);
#pragma unroll
    for (int mi = 0; mi < 4; mi++)
#pragma unroll
      for (int ni = 0; ni < 4; ni++)
        acc[mi][ni] = __builtin_amdgcn_mfma_f32_16x16x32_bf16(af[mi], bfr[ni], acc[mi][ni], 0, 0, 0);
    __syncthreads();
  }

#pragma unroll
  for (int mi = 0; mi < 4; mi++) {
#pragma unroll
    for (int ni = 0; ni < 4; ni++) {
      const int col = h * HD_ + wn + ni * 16 + lr;
#pragma unroll
      for (int r = 0; r < 4; r++) {
        const int sl = m0 + wm + mi * 16 + er + r;
        Ob[(long)(b * S_ + sl) * D_ + col] = (bf16)acc[mi][ni][r];
      }
    }
  }
}

extern "C" void kernel_launch(void* const* d_in, const int* in_sizes, int n_in,
                              void* d_out, int out_size, void* d_ws, size_t ws_size,
                              hipStream_t stream) {
  const float* x   = (const float*)d_in[0];
  const float* wq  = (const float*)d_in[1];
  const float* bq  = (const float*)d_in[2];
  const float* wk  = (const float*)d_in[3];
  const float* bk  = (const float*)d_in[4];
  const float* wv  = (const float*)d_in[5];
  const float* bv  = (const float*)d_in[6];
  const float* wo  = (const float*)d_in[7];
  const float* bo  = (const float*)d_in[8];
  const float* ch  = (const float*)d_in[9];
  const float* sh  = (const float*)d_in[10];
  const float* mask = (const float*)d_in[11];
  float* out = (float*)d_out;

  // Workspace layout (max use ~296 MiB; round-3 run proved ws_size >= 320 MiB):
  //   [0,96M)        QKV        (live: GEMM1 .. pv_gemm)
  //   [96M,128M)     Vt         (live: vtrans .. pv_gemm)
  //   [128M,136M)    wob        (live: f2b4 .. final GEMM)
  //   [136M,+24K)    bqkv
  //   [136.02,169.6) Ob         (live: pv_gemm .. final GEMM)
  //   [168*,200*)    xb         (dead after GEMM1)
  //   [200*,224*)    wqkvb      (dead after GEMM1)
  //   [168*,296*)    Sb         (aliases xb+wqkvb, live only after vtrans)
  char* ws = (char*)d_ws;
  bf16*  QKV   = (bf16*)(ws);                    // 96 MB
  bf16*  Vt    = (bf16*)(ws + 100663296);        // 32 MB
  bf16*  wob   = (bf16*)(ws + 134217728);        // 8 MB
  float* bqkv  = (float*)(ws + 142606336);       // 24 KB
  bf16*  Ob    = (bf16*)(ws + 142630912);        // 32 MB
  bf16*  xb    = (bf16*)(ws + 176185344);        // 32 MB (dead after GEMM1)
  bf16*  wqkvb = (bf16*)(ws + 209739776);        // 24 MB (dead after GEMM1)
  bf16*  Sb    = (bf16*)(ws + 176185344);        // 128 MB, aliases xb+wqkvb

  f2b4<<<16384, 256, 0, stream>>>(x, xb, 4194304);
  f2b4<<<4096, 256, 0, stream>>>(wq, wqkvb,           1048576);
  f2b4<<<4096, 256, 0, stream>>>(wk, wqkvb + 4194304, 1048576);
  f2b4<<<4096, 256, 0, stream>>>(wv, wqkvb + 8388608, 1048576);
  f2b4<<<4096, 256, 0, stream>>>(wo, wob, 1048576);
  packb<<<24, 256, 0, stream>>>(bq, bk, bv, bqkv);

  // QKV = x @ [wq;wk;wv]^T + bias  (8192 x 6144 x 2048)
  gemm_bt<bf16><<<dim3(48, 64), 256, 0, stream>>>(xb, wqkvb, bqkv, QKV, NROW, NQKV, D_);

  rope_qk<<<32768, 256, 0, stream>>>(QKV, ch, sh);
  vtrans<<<1024, 256, 0, stream>>>(QKV, Vt);

  // attention as two batched GEMMs, chunked by 64 (b,h) pairs so the
  // 128 MB score slab stays L3-resident between passes
  for (int bh0 = 0; bh0 < B_ * H_; bh0 += 64) {
    qk_gemm<<<dim3(8, 8, 64), 256, 0, stream>>>(QKV, mask, Sb, bh0);
    pv_gemm<<<dim3(1, 8, 64), 256, 0, stream>>>(Sb, Vt, Ob, bh0);
  }

  // out = a_sum @ wo^T + bo  (8192 x 2048 x 2048), fp32 output
  gemm_bt<float><<<dim3(16, 64), 256, 0, stream>>>(Ob, wob, bo, out, NROW, D_, D_);
}